// Round 8
// baseline (233.174 us; speedup 1.0000x reference)
//
#include <hip/hip_runtime.h>
#include <stdint.h>

typedef unsigned int   u32;
typedef unsigned short u16;
typedef __bf16 bf16x8 __attribute__((ext_vector_type(8)));
typedef float  f32x4  __attribute__((ext_vector_type(4)));
typedef float  f32x16 __attribute__((ext_vector_type(16)));

// ---------------------------------------------------------------------------
// Compile-time DWT analysis matrix Wd[84][64] (db4, reflect, J=3).
// Row order: lo3 (14) | hi1 (35) | hi2 (21) | hi3 (14).
// ---------------------------------------------------------------------------
struct WdT { float v[84][64]; };

constexpr WdT build_wd() {
    WdT W{};
    const float GLc[8] = { 0.23037781330885523f,  0.7148465705525415f,
                           0.6308807679295904f,  -0.02798376941698385f,
                          -0.18703481171888114f,  0.030841381835986965f,
                           0.032883011666982945f,-0.010597401784997278f };
    const float GHc[8] = {-0.010597401784997278f,-0.032883011666982945f,
                           0.030841381835986965f, 0.18703481171888114f,
                          -0.02798376941698385f, -0.6308807679295904f,
                           0.7148465705525415f,  -0.23037781330885523f };
    for (int j = 0; j < 64; ++j) {
        float lo1[35] = {}, lo2[21] = {};
        for (int i = 0; i < 35; ++i) {
            float sl = 0.f, sh = 0.f;
            for (int t = 0; t < 8; ++t) {
                int s = 2*i + t - 6;
                if (s < 0)   s = -s;
                if (s >= 64) s = 126 - s;
                if (s == j) { sl += GLc[t]; sh += GHc[t]; }
            }
            lo1[i] = sl; W.v[14 + i][j] = sh;
        }
        for (int i = 0; i < 21; ++i) {
            float sl = 0.f, sh = 0.f;
            for (int t = 0; t < 8; ++t) {
                int s = 2*i + t - 6;
                if (s < 0)   s = -s;
                if (s >= 36) s = 70 - s;
                if (s < 35) { sl += lo1[s]*GLc[t]; sh += lo1[s]*GHc[t]; }
            }
            lo2[i] = sl; W.v[49 + i][j] = sh;
        }
        for (int i = 0; i < 14; ++i) {
            float sl = 0.f, sh = 0.f;
            for (int t = 0; t < 8; ++t) {
                int s = 2*i + t - 6;
                if (s < 0)   s = -s;
                if (s >= 22) s = 42 - s;
                if (s < 21) { sl += lo2[s]*GLc[t]; sh += lo2[s]*GHc[t]; }
            }
            W.v[i][j] = sl; W.v[70 + i][j] = sh;
        }
    }
    return W;
}

__constant__ WdT WD = build_wd();

__device__ inline u16 f32_bf16(float f) {
    u32 u = __float_as_uint(f);
    u += 0x7fffu + ((u >> 16) & 1u);
    return (u16)(u >> 16);
}
__device__ inline u32 pack2_bf16(float a, float b) {
    u32 ua = __float_as_uint(a); ua += 0x7fffu + ((ua >> 16) & 1u);
    u32 ub = __float_as_uint(b); ub += 0x7fffu + ((ub >> 16) & 1u);
    return (ua >> 16) | (ub & 0xffff0000u);
}

// async 16-byte global -> LDS (fire-and-forget; counted by vmcnt)
typedef const __attribute__((address_space(1))) u32 gas_u32;
typedef __attribute__((address_space(3)))       u32 las_u32;
__device__ inline void gl16(const void* g, void* l) {
    __builtin_amdgcn_global_load_lds((gas_u32*)g, (las_u32*)l, 16, 0, 0);
}

// ---------------------------------------------------------------------------
// Kernel 1: fold conv weights with the constant DWT matrix, emitting bf16 in
// 32x32x16 MFMA B-fragment order, kb-contiguous (kb = 32-wide K block):
//   element (n, K) with K = kb*32 + kh*16 + hb*8 + j  lives at u16 index
//   (((s*128+kb)*2 + kh)*4 + n>>5)*512 + (hb*32 + (n&31))*8 + j
// where Wp[n][K = sigma*64 + hw] = sum_tau cw[s,n,tau,hw] * Wd[tau][sigma],
// i.e. kb = sigma*2 + (hw>>5), kh = (hw>>4)&1, hb = (hw>>3)&1, j = hw&7.
// One block per (s,n).  WD[tau][t0+j] is wave-uniform -> scalar K$ loads.
// ---------------------------------------------------------------------------
__global__ __launch_bounds__(256) void fold_w(const float* __restrict__ cw,
                                              u16* __restrict__ Wf) {
    const int tid = threadIdx.x;
    const int sk  = blockIdx.x;                  // 0..511 = s*128 + n
    const int s   = sk >> 7;
    const int n   = sk & 127;
    const int hw  = tid & 63;
    const int tg  = __builtin_amdgcn_readfirstlane((int)(tid >> 6)); // 0..3
    const int t0  = tg * 16;
    const float* wk = cw + (size_t)sk * (84 * 64);

    float acc[16];
#pragma unroll
    for (int j = 0; j < 16; ++j) acc[j] = 0.f;

#pragma unroll 4
    for (int tau = 0; tau < 84; ++tau) {
        const float wv = wk[tau * 64 + hw];      // coalesced 256 B / wave
#pragma unroll
        for (int j = 0; j < 16; ++j) acc[j] += wv * WD.v[tau][t0 + j]; // s_load
    }

    const int kh = (hw >> 4) & 1;
    const int hb = (hw >> 3) & 1;
    const int jj = hw & 7;
    const int nt = n >> 5;
    const int lb = hb * 32 + (n & 31);
#pragma unroll
    for (int js = 0; js < 16; ++js) {
        const int sigma = t0 + js;
        const int kb = sigma * 2 + (hw >> 5);
        const size_t idx =
            ((((size_t)(s * 128 + kb) * 2 + kh) * 4 + nt) * 512) + lb * 8 + jj;
        Wf[idx] = f32_bf16(acc[js]);
    }
}

// ---------------------------------------------------------------------------
// Kernel 2: LDS-staged MFMA GEMM using 32x32x16 (4x FLOP per fragment byte).
// Grid 64*KQ (XCD-swizzled) = kq x s x mt; 256 thr = 4 waves, wave w owns
// rows [mt*128 + w*32, +32) x full 128 n.  BK=32, NSTEP=(4096/KQ)/32 stages,
// 2-deep pipeline, counted vmcnt(6).  A: 16 KB/stage via gl16, XOR-swizzled
// SOURCE (linear LDS dest), reads via two per-half b128s (handles the
// halfpair swap).  B: 8 KB/stage linear (fragment-ordered Wf, L2-resident).
// Partials to P[kq]; reduce_k finishes.
// ---------------------------------------------------------------------------
template <int KQ>
__global__ __launch_bounds__(256, 2) void gemm_f(const float* __restrict__ X,
                                                 const u16* __restrict__ Wf,
                                                 float* __restrict__ P) {
    constexpr int NSTEP = (4096 / KQ) / 32;      // 16 for KQ=8
    __shared__ float As[2][4096];                // [128 m][32 k] fp32, 16 KB x2
    __shared__ u16   Bs[2][4096];                // [kh2][nt4][lane64][j8], 8 KB x2

    const int tid  = threadIdx.x;
    const int lane = tid & 63;
    const int w    = tid >> 6;                   // wave 0..3 = m-band
    const int col  = lane & 31;                  // MFMA row/col index
    const int hi   = lane >> 5;

    const int bid  = blockIdx.x;                 // grid 64*KQ, %8==0
    const int wg   = (bid & 7) * (8 * KQ) + (bid >> 3);   // XCD-chunked
    const int mt   = wg & 15;
    const int s    = (wg >> 4) & 3;
    const int kq   = wg >> 6;                    // 0..KQ-1

    // A staging: thread t, issue i: LDS byte i*4096 + t*16 -> m = i*32+(t>>3),
    // in-row byte ((t&7)*16) ^ ((m&7)<<4) of the stage's 128-B row chunk.
    const int am = tid >> 3;                     // 0..31 (m&7 invariant per +32)
    const int ab = ((tid & 7) * 16) ^ ((am & 7) << 4);
    const float* xa = X + (size_t)(mt * 128 + am) * 16384 + s * 4096
                        + kq * (4096 / KQ) + (ab >> 2);
    // B staging: thread t stages bytes t*16 (+4096) of the stage's 8 KB chunk.
    const char* wb0 = (const char*)Wf + (size_t)(s * 128 + kq * NSTEP) * 8192
                        + (size_t)tid * 16;

    f32x16 acc[4];
#pragma unroll
    for (int nt = 0; nt < 4; ++nt)
#pragma unroll
        for (int e = 0; e < 16; ++e) acc[nt][e] = 0.f;

#define STAGE(buf, st)                                                         \
    do {                                                                       \
        char* la = (char*)&As[buf][0] + tid * 16;                              \
        const float* ga = xa + (size_t)(st) * 32;                              \
        gl16(ga,               la);                                            \
        gl16(ga + 32 * 16384,  la + 4096);                                     \
        gl16(ga + 64 * 16384,  la + 8192);                                     \
        gl16(ga + 96 * 16384,  la + 12288);                                    \
        const char* gb = wb0 + (size_t)(st) * 8192;                            \
        char*       lb = (char*)&Bs[buf][0] + tid * 16;                        \
        gl16(gb,        lb);                                                   \
        gl16(gb + 4096, lb + 4096);                                            \
    } while (0)

    STAGE(0, 0);

    const int m  = w * 32 + col;                 // row within 128-tile
    const int m7 = col & 7;                      // m&7 (w*32 ≡ 0 mod 8)
#pragma unroll 2
    for (int step = 0; step < NSTEP; ++step) {
        const int buf = step & 1;
        if (step + 1 < NSTEP) {
            STAGE(buf ^ 1, step + 1);
            asm volatile("s_waitcnt vmcnt(6)" ::: "memory"); // cur landed; next in flight
        } else {
            asm volatile("s_waitcnt vmcnt(0)" ::: "memory");
        }
        __builtin_amdgcn_s_barrier();

        const char* Ab = (const char*)&As[buf][0];
        const u16*  Bb = &Bs[buf][0];
#pragma unroll
        for (int kh = 0; kh < 2; ++kh) {
            const int c = kh * 4 + hi * 2;       // 16B-chunk idx of k-half
            const f32x4 r0 = *reinterpret_cast<const f32x4*>(
                Ab + m * 128 + (((c    ) ^ m7) << 4));
            const f32x4 r1 = *reinterpret_cast<const f32x4*>(
                Ab + m * 128 + (((c + 1) ^ m7) << 4));
            union { u32 u[4]; bf16x8 v; } av;
            av.u[0] = pack2_bf16(r0.x, r0.y); av.u[1] = pack2_bf16(r0.z, r0.w);
            av.u[2] = pack2_bf16(r1.x, r1.y); av.u[3] = pack2_bf16(r1.z, r1.w);
#pragma unroll
            for (int nt = 0; nt < 4; ++nt) {
                const bf16x8 bf = *reinterpret_cast<const bf16x8*>(
                    Bb + ((kh * 4 + nt) * 64 + lane) * 8);
                acc[nt] = __builtin_amdgcn_mfma_f32_32x32x16_bf16(
                    av.v, bf, acc[nt], 0, 0, 0);
            }
        }

        asm volatile("s_waitcnt lgkmcnt(0)" ::: "memory");   // my ds_reads done
        __builtin_amdgcn_s_barrier();                        // safe to overwrite
    }
#undef STAGE

    // C layout (verified m74/m101): col = lane&31, row = (reg&3)+8*(reg>>2)+4*hi
    float* pg = P + (size_t)kq * (2048 * 512)
                  + (size_t)(mt * 128 + w * 32 + hi * 4) * 512 + s * 128 + col;
#pragma unroll
    for (int nt = 0; nt < 4; ++nt)
#pragma unroll
        for (int q = 0; q < 4; ++q)
#pragma unroll
            for (int r = 0; r < 4; ++r)
                pg[(size_t)(q * 8 + r) * 512 + nt * 32] = acc[nt][q * 4 + r];
}

// ---------------------------------------------------------------------------
// Kernel 3: reduce K-slices, add bias, leaky-ReLU.
// ---------------------------------------------------------------------------
__global__ __launch_bounds__(256) void reduce_k(const float* __restrict__ P,
                                                const float* __restrict__ bias,
                                                float* __restrict__ out, int nks) {
    const int t = blockIdx.x * 256 + threadIdx.x;     // 0..262143
    const size_t base = (size_t)t * 4;
    f32x4 sum = {0.f, 0.f, 0.f, 0.f};
    for (int k = 0; k < nks; ++k)
        sum += *reinterpret_cast<const f32x4*>(P + (size_t)k * (2048 * 512) + base);
    const f32x4 b = *reinterpret_cast<const f32x4*>(bias + (base & 511));
    f32x4 o = sum + b;
    o.x = o.x > 0.f ? o.x : 0.01f * o.x;
    o.y = o.y > 0.f ? o.y : 0.01f * o.y;
    o.z = o.z > 0.f ? o.z : 0.01f * o.z;
    o.w = o.w > 0.f ? o.w : 0.01f * o.w;
    __builtin_nontemporal_store(o, reinterpret_cast<f32x4*>(out + base));
}

// ---------------------------------------------------------------------------
extern "C" void kernel_launch(void* const* d_in, const int* in_sizes, int n_in,
                              void* d_out, int out_size, void* d_ws, size_t ws_size,
                              hipStream_t stream) {
    const float* x  = (const float*)d_in[0];   // [2048,1,256,8,8] fp32
    const float* cw = (const float*)d_in[1];   // [4,128,84,8,8]   fp32
    const float* cb = (const float*)d_in[2];   // [4,128]          fp32
    float* out = (float*)d_out;                // [2048,512]       fp32

    u16*   Wf = (u16*)d_ws;                              // 4 MiB
    float* P  = (float*)((char*)d_ws + (4u << 20));      // KQ * 4 MiB partials

    const size_t MN = (size_t)2048 * 512 * 4;
    fold_w<<<512, 256, 0, stream>>>(cw, Wf);
    if (ws_size >= (4u << 20) + 8 * MN) {
        gemm_f<8><<<512, 256, 0, stream>>>(x, Wf, P);
        reduce_k<<<1024, 256, 0, stream>>>(P, cb, out, 8);
    } else {
        gemm_f<4><<<256, 256, 0, stream>>>(x, Wf, P);
        reduce_k<<<1024, 256, 0, stream>>>(P, cb, out, 4);
    }
}

// Round 9
// 230.992 us; speedup vs baseline: 1.0094x; 1.0094x over previous
//
#include <hip/hip_runtime.h>
#include <stdint.h>

typedef unsigned int   u32;
typedef unsigned short u16;
typedef __bf16 bf16x8 __attribute__((ext_vector_type(8)));
typedef float  f32x4  __attribute__((ext_vector_type(4)));
typedef float  f32x16 __attribute__((ext_vector_type(16)));

// ---------------------------------------------------------------------------
// Compile-time DWT analysis matrix Wd[84][64] (db4, reflect, J=3).
// Row order: lo3 (14) | hi1 (35) | hi2 (21) | hi3 (14).
// ---------------------------------------------------------------------------
struct WdT { float v[84][64]; };

constexpr WdT build_wd() {
    WdT W{};
    const float GLc[8] = { 0.23037781330885523f,  0.7148465705525415f,
                           0.6308807679295904f,  -0.02798376941698385f,
                          -0.18703481171888114f,  0.030841381835986965f,
                           0.032883011666982945f,-0.010597401784997278f };
    const float GHc[8] = {-0.010597401784997278f,-0.032883011666982945f,
                           0.030841381835986965f, 0.18703481171888114f,
                          -0.02798376941698385f, -0.6308807679295904f,
                           0.7148465705525415f,  -0.23037781330885523f };
    for (int j = 0; j < 64; ++j) {
        float lo1[35] = {}, lo2[21] = {};
        for (int i = 0; i < 35; ++i) {
            float sl = 0.f, sh = 0.f;
            for (int t = 0; t < 8; ++t) {
                int s = 2*i + t - 6;
                if (s < 0)   s = -s;
                if (s >= 64) s = 126 - s;
                if (s == j) { sl += GLc[t]; sh += GHc[t]; }
            }
            lo1[i] = sl; W.v[14 + i][j] = sh;
        }
        for (int i = 0; i < 21; ++i) {
            float sl = 0.f, sh = 0.f;
            for (int t = 0; t < 8; ++t) {
                int s = 2*i + t - 6;
                if (s < 0)   s = -s;
                if (s >= 36) s = 70 - s;
                if (s < 35) { sl += lo1[s]*GLc[t]; sh += lo1[s]*GHc[t]; }
            }
            lo2[i] = sl; W.v[49 + i][j] = sh;
        }
        for (int i = 0; i < 14; ++i) {
            float sl = 0.f, sh = 0.f;
            for (int t = 0; t < 8; ++t) {
                int s = 2*i + t - 6;
                if (s < 0)   s = -s;
                if (s >= 22) s = 42 - s;
                if (s < 21) { sl += lo2[s]*GLc[t]; sh += lo2[s]*GHc[t]; }
            }
            W.v[i][j] = sl; W.v[70 + i][j] = sh;
        }
    }
    return W;
}

__constant__ WdT WD = build_wd();

__device__ inline u16 f32_bf16(float f) {
    u32 u = __float_as_uint(f);
    u += 0x7fffu + ((u >> 16) & 1u);
    return (u16)(u >> 16);
}
__device__ inline u32 pack2_bf16(float a, float b) {
    u32 ua = __float_as_uint(a); ua += 0x7fffu + ((ua >> 16) & 1u);
    u32 ub = __float_as_uint(b); ub += 0x7fffu + ((ub >> 16) & 1u);
    return (ua >> 16) | (ub & 0xffff0000u);
}

// async 16-byte global -> LDS (fire-and-forget; counted by vmcnt)
typedef const __attribute__((address_space(1))) u32 gas_u32;
typedef __attribute__((address_space(3)))       u32 las_u32;
__device__ inline void gl16(const void* g, void* l) {
    __builtin_amdgcn_global_load_lds((gas_u32*)g, (las_u32*)l, 16, 0, 0);
}

// ---------------------------------------------------------------------------
// Kernel 1: fold conv weights with the constant DWT matrix, emitting bf16 in
// 32x32x16 MFMA B-fragment order, kb-contiguous (kb = 32-wide K block):
//   element (n, K) with K = kb*32 + kh*16 + hb*8 + j  lives at u16 index
//   (((s*128+kb)*2 + kh)*4 + n>>5)*512 + (hb*32 + (n&31))*8 + j
// where Wp[n][K = sigma*64 + hw] = sum_tau cw[s,n,tau,hw] * Wd[tau][sigma],
// i.e. kb = sigma*2 + (hw>>5), kh = (hw>>4)&1, hb = (hw>>3)&1, j = hw&7.
// One block per (s,n).  WD[tau][t0+j] is wave-uniform -> scalar K$ loads.
// ---------------------------------------------------------------------------
__global__ __launch_bounds__(256) void fold_w(const float* __restrict__ cw,
                                              u16* __restrict__ Wf) {
    const int tid = threadIdx.x;
    const int sk  = blockIdx.x;                  // 0..511 = s*128 + n
    const int s   = sk >> 7;
    const int n   = sk & 127;
    const int hw  = tid & 63;
    const int tg  = __builtin_amdgcn_readfirstlane((int)(tid >> 6)); // 0..3
    const int t0  = tg * 16;
    const float* wk = cw + (size_t)sk * (84 * 64);

    float acc[16];
#pragma unroll
    for (int j = 0; j < 16; ++j) acc[j] = 0.f;

#pragma unroll 4
    for (int tau = 0; tau < 84; ++tau) {
        const float wv = wk[tau * 64 + hw];      // coalesced 256 B / wave
#pragma unroll
        for (int j = 0; j < 16; ++j) acc[j] += wv * WD.v[tau][t0 + j]; // s_load
    }

    const int kh = (hw >> 4) & 1;
    const int hb = (hw >> 3) & 1;
    const int jj = hw & 7;
    const int nt = n >> 5;
    const int lb = hb * 32 + (n & 31);
#pragma unroll
    for (int js = 0; js < 16; ++js) {
        const int sigma = t0 + js;
        const int kb = sigma * 2 + (hw >> 5);
        const size_t idx =
            ((((size_t)(s * 128 + kb) * 2 + kh) * 4 + nt) * 512) + lb * 8 + jj;
        Wf[idx] = f32_bf16(acc[js]);
    }
}

// ---------------------------------------------------------------------------
// Kernel 2: LDS-staged MFMA GEMM (32x32x16) with CIRCULAR per-block K-order.
// Identical to R8 except: block with m-tile mt processes physical stage
// (mt + step) & (NSTEP-1).  At any instant the grid's active A-column
// offsets cover the full 64 KB row width densely (4s x 8kq x 16 phases x
// 128 B) instead of 32 lockstep offsets -> spreads reads across ALL HBM
// channels (fixes the ~2 TB/s channel-camping wall seen in R0/R4/R5/R6/R8).
// K-order permutation is exact for GEMM accumulation.
// ---------------------------------------------------------------------------
template <int KQ>
__global__ __launch_bounds__(256, 2) void gemm_f(const float* __restrict__ X,
                                                 const u16* __restrict__ Wf,
                                                 float* __restrict__ P) {
    constexpr int NSTEP = (4096 / KQ) / 32;      // 16 for KQ=8 (pow2)
    __shared__ float As[2][4096];                // [128 m][32 k] fp32, 16 KB x2
    __shared__ u16   Bs[2][4096];                // [kh2][nt4][lane64][j8], 8 KB x2

    const int tid  = threadIdx.x;
    const int lane = tid & 63;
    const int w    = tid >> 6;                   // wave 0..3 = m-band
    const int col  = lane & 31;                  // MFMA row/col index
    const int hi   = lane >> 5;

    const int bid  = blockIdx.x;                 // grid 64*KQ, %8==0
    const int wg   = (bid & 7) * (8 * KQ) + (bid >> 3);   // XCD-chunked
    const int mt   = wg & 15;
    const int s    = (wg >> 4) & 3;
    const int kq   = wg >> 6;                    // 0..KQ-1

    // A staging: thread t, issue i: LDS byte i*4096 + t*16 -> m = i*32+(t>>3),
    // in-row byte ((t&7)*16) ^ ((m&7)<<4) of the stage's 128-B row chunk.
    const int am = tid >> 3;                     // 0..31 (m&7 invariant per +32)
    const int ab = ((tid & 7) * 16) ^ ((am & 7) << 4);
    const float* xa = X + (size_t)(mt * 128 + am) * 16384 + s * 4096
                        + kq * (4096 / KQ) + (ab >> 2);
    // B staging: thread t stages bytes t*16 (+4096) of the stage's 8 KB chunk.
    const char* wb0 = (const char*)Wf + (size_t)(s * 128 + kq * NSTEP) * 8192
                        + (size_t)tid * 16;

    f32x16 acc[4];
#pragma unroll
    for (int nt = 0; nt < 4; ++nt)
#pragma unroll
        for (int e = 0; e < 16; ++e) acc[nt][e] = 0.f;

#define STAGE(buf, st)                                                         \
    do {                                                                       \
        char* la = (char*)&As[buf][0] + tid * 16;                              \
        const float* ga = xa + (size_t)(st) * 32;                              \
        gl16(ga,               la);                                            \
        gl16(ga + 32 * 16384,  la + 4096);                                     \
        gl16(ga + 64 * 16384,  la + 8192);                                     \
        gl16(ga + 96 * 16384,  la + 12288);                                    \
        const char* gb = wb0 + (size_t)(st) * 8192;                            \
        char*       lb = (char*)&Bs[buf][0] + tid * 16;                        \
        gl16(gb,        lb);                                                   \
        gl16(gb + 4096, lb + 4096);                                            \
    } while (0)

    // circular K-order: physical stage = (mt + step) mod NSTEP
    STAGE(0, (mt & (NSTEP - 1)));

    const int m  = w * 32 + col;                 // row within 128-tile
    const int m7 = col & 7;                      // m&7 (w*32 ≡ 0 mod 8)
#pragma unroll 2
    for (int step = 0; step < NSTEP; ++step) {
        const int buf = step & 1;
        if (step + 1 < NSTEP) {
            STAGE(buf ^ 1, ((mt + step + 1) & (NSTEP - 1)));
            asm volatile("s_waitcnt vmcnt(6)" ::: "memory"); // cur landed; next in flight
        } else {
            asm volatile("s_waitcnt vmcnt(0)" ::: "memory");
        }
        __builtin_amdgcn_s_barrier();

        const char* Ab = (const char*)&As[buf][0];
        const u16*  Bb = &Bs[buf][0];
#pragma unroll
        for (int kh = 0; kh < 2; ++kh) {
            const int c = kh * 4 + hi * 2;       // 16B-chunk idx of k-half
            const f32x4 r0 = *reinterpret_cast<const f32x4*>(
                Ab + m * 128 + (((c    ) ^ m7) << 4));
            const f32x4 r1 = *reinterpret_cast<const f32x4*>(
                Ab + m * 128 + (((c + 1) ^ m7) << 4));
            union { u32 u[4]; bf16x8 v; } av;
            av.u[0] = pack2_bf16(r0.x, r0.y); av.u[1] = pack2_bf16(r0.z, r0.w);
            av.u[2] = pack2_bf16(r1.x, r1.y); av.u[3] = pack2_bf16(r1.z, r1.w);
#pragma unroll
            for (int nt = 0; nt < 4; ++nt) {
                const bf16x8 bf = *reinterpret_cast<const bf16x8*>(
                    Bb + ((kh * 4 + nt) * 64 + lane) * 8);
                acc[nt] = __builtin_amdgcn_mfma_f32_32x32x16_bf16(
                    av.v, bf, acc[nt], 0, 0, 0);
            }
        }

        asm volatile("s_waitcnt lgkmcnt(0)" ::: "memory");   // my ds_reads done
        __builtin_amdgcn_s_barrier();                        // safe to overwrite
    }
#undef STAGE

    // C layout (verified m74/m101): col = lane&31, row = (reg&3)+8*(reg>>2)+4*hi
    float* pg = P + (size_t)kq * (2048 * 512)
                  + (size_t)(mt * 128 + w * 32 + hi * 4) * 512 + s * 128 + col;
#pragma unroll
    for (int nt = 0; nt < 4; ++nt)
#pragma unroll
        for (int q = 0; q < 4; ++q)
#pragma unroll
            for (int r = 0; r < 4; ++r)
                pg[(size_t)(q * 8 + r) * 512 + nt * 32] = acc[nt][q * 4 + r];
}

// ---------------------------------------------------------------------------
// Kernel 3: reduce K-slices, add bias, leaky-ReLU.
// ---------------------------------------------------------------------------
__global__ __launch_bounds__(256) void reduce_k(const float* __restrict__ P,
                                                const float* __restrict__ bias,
                                                float* __restrict__ out, int nks) {
    const int t = blockIdx.x * 256 + threadIdx.x;     // 0..262143
    const size_t base = (size_t)t * 4;
    f32x4 sum = {0.f, 0.f, 0.f, 0.f};
    for (int k = 0; k < nks; ++k)
        sum += *reinterpret_cast<const f32x4*>(P + (size_t)k * (2048 * 512) + base);
    const f32x4 b = *reinterpret_cast<const f32x4*>(bias + (base & 511));
    f32x4 o = sum + b;
    o.x = o.x > 0.f ? o.x : 0.01f * o.x;
    o.y = o.y > 0.f ? o.y : 0.01f * o.y;
    o.z = o.z > 0.f ? o.z : 0.01f * o.z;
    o.w = o.w > 0.f ? o.w : 0.01f * o.w;
    __builtin_nontemporal_store(o, reinterpret_cast<f32x4*>(out + base));
}

// ---------------------------------------------------------------------------
extern "C" void kernel_launch(void* const* d_in, const int* in_sizes, int n_in,
                              void* d_out, int out_size, void* d_ws, size_t ws_size,
                              hipStream_t stream) {
    const float* x  = (const float*)d_in[0];   // [2048,1,256,8,8] fp32
    const float* cw = (const float*)d_in[1];   // [4,128,84,8,8]   fp32
    const float* cb = (const float*)d_in[2];   // [4,128]          fp32
    float* out = (float*)d_out;                // [2048,512]       fp32

    u16*   Wf = (u16*)d_ws;                              // 4 MiB
    float* P  = (float*)((char*)d_ws + (4u << 20));      // KQ * 4 MiB partials

    const size_t MN = (size_t)2048 * 512 * 4;
    fold_w<<<512, 256, 0, stream>>>(cw, Wf);
    if (ws_size >= (4u << 20) + 8 * MN) {
        gemm_f<8><<<512, 256, 0, stream>>>(x, Wf, P);
        reduce_k<<<1024, 256, 0, stream>>>(P, cb, out, 8);
    } else {
        gemm_f<4><<<256, 256, 0, stream>>>(x, Wf, P);
        reduce_k<<<1024, 256, 0, stream>>>(P, cb, out, 4);
    }
}